// Round 11
// baseline (71.691 us; speedup 1.0000x reference)
//
#include <hip/hip_runtime.h>
#include <hip/hip_bf16.h>
#include <stdint.h>

#define NROWS 100000
#define INDIM 512
#define HID 128
#define NCLS 10
#define LEAKY_ALPHA 0.2f
#define GSTR 24   // G row stride (f32)

typedef __bf16 bf16x8_t __attribute__((ext_vector_type(8)));
typedef __bf16 bf16x4_t __attribute__((ext_vector_type(4)));
typedef float f32x4_t __attribute__((ext_vector_type(4)));
typedef unsigned short ushort8_t __attribute__((ext_vector_type(8)));

union Frag {
    bf16x8_t v8;
    bf16x4_t v4[2];
    unsigned short u[8];
};

__device__ __forceinline__ unsigned short f2bf(float x) {
    union { __hip_bfloat16 b; unsigned short u; } cv;
    cv.b = __float2bfloat16(x);
    return cv.u;
}

// Byte address inside an [R x 32] bf16 tile image (rows paired into 128-B
// lines, 16-B units XOR-swizzled by pair&7). Bank-verified round 3.
__device__ __forceinline__ int img_addr(int r, int kk) {
    int p = r >> 1;
    int o = ((r & 1) << 6) | (kk << 1);
    return (p << 7) | ((((o >> 4) ^ (p & 7)) << 4) | (o & 15));
}

__device__ __forceinline__ void gload_lds16(const void* g, void* l) {
    __builtin_amdgcn_global_load_lds(
        (const __attribute__((address_space(1))) unsigned int*)g,
        (__attribute__((address_space(3))) unsigned int*)l, 16, 0, 0);
}

// ---------------- prep: Qimg = swizzled tile images of Q = [C@(W1@V) | C@(W2@V)] ----------------
__global__ __launch_bounds__(256) void k_prep(
    const float* __restrict__ C, const float* __restrict__ W, const float* __restrict__ V,
    unsigned short* __restrict__ Qimg) {
    __shared__ float Vl[HID * NCLS];
    __shared__ float Pl[2][HID][10];
    __shared__ float Cl[32][132];

    const int tid = threadIdx.x, b = blockIdx.x;
    for (int i = tid; i < HID * NCLS; i += 256) Vl[i] = V[i];
    __syncthreads();

    {
        const int half = tid >> 7, j = tid & 127;
        const float* wr = W + (half * HID + j) * HID;
        float s[NCLS];
#pragma unroll
        for (int c = 0; c < NCLS; ++c) s[c] = 0.f;
        for (int m = 0; m < HID; m += 4) {
            float4 wv = *reinterpret_cast<const float4*>(wr + m);
            float wa[4] = {wv.x, wv.y, wv.z, wv.w};
#pragma unroll
            for (int u = 0; u < 4; ++u)
#pragma unroll
                for (int c = 0; c < NCLS; ++c) s[c] += wa[u] * Vl[(m + u) * NCLS + c];
        }
#pragma unroll
        for (int c = 0; c < NCLS; ++c) Pl[half][j][c] = s[c];
    }
    const int k0 = b << 5;
    {
        const int kr = tid >> 3, ns = (tid & 7) << 4;
        const float4* src = reinterpret_cast<const float4*>(C + (k0 + kr) * HID + ns);
#pragma unroll
        for (int j = 0; j < 4; ++j)
            *reinterpret_cast<float4*>(&Cl[kr][ns + 4 * j]) = src[j];
    }
    __syncthreads();

    for (int e = tid; e < 32 * 32; e += 256) {
        const int n = e >> 5, kl = e & 31;
        const int half = n >> 4, c = n & 15;
        float s = 0.f;
        if (c < NCLS) {
#pragma unroll 4
            for (int j = 0; j < HID; ++j) s += Cl[kl][j] * Pl[half][j][c];
        }
        *(unsigned short*)((char*)Qimg + b * 2048 + img_addr(n, kl)) = f2bf(s);
    }
}

// ---------------- thin GEMM: g = f @ Q  (BK=128: 512 B/row/visit page granule) ----------------
// BM=128, 4 waves, 4 K-chunks of 128. A staged bf16 single-buffer (32 KB =
// 4 side-by-side 32-k tile images), wave-private rows -> barrier-free loop.
// Per iteration each thread streams 64 contiguous floats (16 outstanding
// float4 loads = ILP latency cover). Q (32 KB) staged once. 64 KB -> 2 blk/CU.
__global__ __launch_bounds__(256, 2) void k_gemm(
    const float* __restrict__ A,             // [NROWS][512] f32
    const unsigned short* __restrict__ Qimg, // 16 x 2KB swizzled tile images
    float* __restrict__ G)                   // [NROWS][GSTR] f32
{
    __shared__ unsigned short Qs[16384];     // 32 KB
    __shared__ unsigned short As[16384];     // 32 KB: 4 images of [128 rows x 32 k]

    const int tid  = threadIdx.x;
    const int w    = tid >> 6;
    const int lane = tid & 63;
    const int l15  = lane & 15;
    const int kg   = (lane >> 4) << 2;
    const long row0 = (long)blockIdx.x * 128;

    // stage all of Q once (wave-uniform dests)
#pragma unroll
    for (int j = 0; j < 8; ++j) {
        const int off = (j * 4 + w) * 1024;
        gload_lds16((const char*)Qimg + off + lane * 16, (char*)Qs + off);
    }

    // A staging: thread -> (row tid>>1, 64-float half of the 128-k chunk)
    const int ar_s = tid >> 1;           // row 0..127 (wave-private: rows 32w..)
    const int hk   = (tid & 1) << 6;     // 0 or 64 floats within chunk
    long gr = row0 + ar_s;
    if (gr >= NROWS) gr = NROWS - 1;
    const float* asrc = A + gr * INDIM + hk;
    // store addresses: subtiles s0, s0+1; ushort8 at kseg 0,8,16,24 each
    const int s0 = hk >> 5;              // 0 or 2
    int awr[8];
#pragma unroll
    for (int u = 0; u < 8; ++u)
        awr[u] = (s0 + (u >> 2)) * 8192 + img_addr(ar_s, (u & 3) * 8);

    // fragment read byte-addresses (within one 8 KB image)
    int ard0[2], ard1[2], brd0[2], brd1[2];
#pragma unroll
    for (int ii = 0; ii < 2; ++ii) {
        int r = w * 32 + ii * 16 + l15;
        ard0[ii] = img_addr(r, kg);
        ard1[ii] = img_addr(r, kg + 16);
    }
#pragma unroll
    for (int f = 0; f < 2; ++f) {
        brd0[f] = img_addr(f * 16 + l15, kg);
        brd1[f] = img_addr(f * 16 + l15, kg + 16);
    }

    f32x4_t acc[2][2];
#pragma unroll
    for (int i = 0; i < 2; ++i)
#pragma unroll
        for (int f = 0; f < 2; ++f)
#pragma unroll
            for (int r = 0; r < 4; ++r) acc[i][f][r] = 0.f;

    const char* asb = (const char*)&As[0];
    const char* bsb = (const char*)&Qs[0];

    // prologue: stage chunk 0 (64 floats -> 8 swizzled ushort8 stores)
    {
        float4 v[16];
#pragma unroll
        for (int j = 0; j < 16; ++j) v[j] = *reinterpret_cast<const float4*>(asrc + 4 * j);
#pragma unroll
        for (int u = 0; u < 8; ++u) {
            ushort8_t pk;
#pragma unroll
            for (int e = 0; e < 4; ++e) {
                pk[e]     = f2bf(v[2 * u][e]);
                pk[4 + e] = f2bf(v[2 * u + 1][e]);
            }
            *(ushort8_t*)((char*)asb + awr[u]) = pk;
        }
    }
    __syncthreads();   // the ONLY barrier: Q + all waves' chunk-0 visible

#pragma unroll
    for (int t = 0; t < 4; ++t) {
        float4 nx[16];
        if (t < 3) {
            // issue next chunk's 16 loads up-front (ILP cover under MFMA phase)
            const float* src = asrc + (t + 1) * 128;
#pragma unroll
            for (int j = 0; j < 16; ++j) nx[j] = *reinterpret_cast<const float4*>(src + 4 * j);
        }

        // 4 k-steps from the 4 subtile images of the current chunk
#pragma unroll
        for (int s = 0; s < 4; ++s) {
            Frag fa[2], fb[2];
#pragma unroll
            for (int ii = 0; ii < 2; ++ii) {
                fa[ii].v4[0] = *(const bf16x4_t*)(asb + s * 8192 + ard0[ii]);
                fa[ii].v4[1] = *(const bf16x4_t*)(asb + s * 8192 + ard1[ii]);
            }
            const int qt = t * 4 + s;
#pragma unroll
            for (int f = 0; f < 2; ++f) {
                fb[f].v4[0] = *(const bf16x4_t*)(bsb + qt * 2048 + brd0[f]);
                fb[f].v4[1] = *(const bf16x4_t*)(bsb + qt * 2048 + brd1[f]);
            }
#pragma unroll
            for (int ii = 0; ii < 2; ++ii)
#pragma unroll
                for (int f = 0; f < 2; ++f)
                    acc[ii][f] = __builtin_amdgcn_mfma_f32_16x16x32_bf16(fa[ii].v8, fb[f].v8, acc[ii][f], 0, 0, 0);
        }

        if (t < 3) {
            // write-late: convert + store chunk t+1 (after this chunk's reads;
            // wave-private rows + in-order DS pipe make this race-free)
#pragma unroll
            for (int u = 0; u < 8; ++u) {
                ushort8_t pk;
#pragma unroll
                for (int e = 0; e < 4; ++e) {
                    pk[e]     = f2bf(nx[2 * u][e]);
                    pk[4 + e] = f2bf(nx[2 * u + 1][e]);
                }
                *(ushort8_t*)((char*)asb + awr[u]) = pk;
            }
        }
    }

    // epilogue: G[row][l15] = f@Q1, G[row][12+l15] = f@Q2
    const int rq_ = (lane >> 4) << 2;
#pragma unroll
    for (int ii = 0; ii < 2; ++ii)
#pragma unroll
        for (int r = 0; r < 4; ++r) {
            long grow = row0 + w * 32 + ii * 16 + rq_ + r;
            if (l15 < NCLS && grow < NROWS) {
                G[grow * GSTR + l15]      = acc[ii][0][r];
                G[grow * GSTR + 12 + l15] = acc[ii][1][r];
            }
        }
}

// ---------------- epilogue: logits = leaky(g[n1][0:10] + g[n2][12:22]), log_softmax ----------------
__global__ __launch_bounds__(256) void k_epi(
    const float* __restrict__ G,
    const int* __restrict__ n1, const int* __restrict__ n2,
    float* __restrict__ Out) {
    const long i = (long)blockIdx.x * 256 + threadIdx.x;
    if (i >= NROWS) return;
    const float* g1 = G + (long)n1[i] * GSTR;
    const float* g2 = G + (long)n2[i] * GSTR + 12;

    float4 a0 = *(const float4*)(g1);
    float4 a1 = *(const float4*)(g1 + 4);
    float2 a2 = *(const float2*)(g1 + 8);
    float4 b0 = *(const float4*)(g2);
    float4 b1 = *(const float4*)(g2 + 4);
    float2 b2 = *(const float2*)(g2 + 8);

    float x[NCLS] = {a0.x + b0.x, a0.y + b0.y, a0.z + b0.z, a0.w + b0.w,
                     a1.x + b1.x, a1.y + b1.y, a1.z + b1.z, a1.w + b1.w,
                     a2.x + b2.x, a2.y + b2.y};
    float m = -1e30f;
#pragma unroll
    for (int c = 0; c < NCLS; ++c) {
        x[c] = (x[c] >= 0.f) ? x[c] : LEAKY_ALPHA * x[c];
        m = fmaxf(m, x[c]);
    }
    float sum = 0.f;
#pragma unroll
    for (int c = 0; c < NCLS; ++c) sum += __expf(x[c] - m);
    const float lse = m + __logf(sum);
    float2* o = (float2*)(Out + i * NCLS);
#pragma unroll
    for (int j = 0; j < 5; ++j) {
        float2 v = {x[2 * j] - lse, x[2 * j + 1] - lse};
        o[j] = v;
    }
}

extern "C" void kernel_launch(void* const* d_in, const int* in_sizes, int n_in,
                              void* d_out, int out_size, void* d_ws, size_t ws_size,
                              hipStream_t stream) {
    const float* features = (const float*)d_in[0];
    const float* C  = (const float*)d_in[1];
    const float* W  = (const float*)d_in[2];
    const float* V  = (const float*)d_in[3];
    const int*   n1 = (const int*)d_in[4];
    const int*   n2 = (const int*)d_in[5];
    float* out = (float*)d_out;

    char* ws = (char*)d_ws;
    unsigned short* Qimg = (unsigned short*)ws;   // 32 KB
    float* G = (float*)(ws + 32768);              // 100000*24*4 = 9.6 MB

    hipLaunchKernelGGL(k_prep, dim3(16), dim3(256), 0, stream, C, W, V, Qimg);
    hipLaunchKernelGGL(k_gemm, dim3((NROWS + 127) / 128), dim3(256), 0, stream,
                       features, Qimg, G);
    hipLaunchKernelGGL(k_epi, dim3((NROWS + 255) / 256), dim3(256), 0, stream,
                       G, n1, n2, out);
}